// Round 1
// baseline (569.910 us; speedup 1.0000x reference)
//
#include <hip/hip_runtime.h>
#include <math.h>

// Problem constants (match reference)
#define BB 16384
#define DD 128
#define LL 20
#define TPR 16                    // threads cooperating per xw row
#define RPB 16                    // rows per block
#define THREADS (TPR * RPB)       // 256
#define CHUNKS (DD / 4)           // 32 float4 chunks per row

// Grid = 1024 blocks (4 per CU -> 16 waves/CU, 4/SIMD for latency hiding;
// previous version had 1 block/CU = 1 wave/SIMD, fully latency-exposed).
// Each block stages the 20 gathered W rows (10 KB) in LDS; 16 threads
// cooperate per xw row: thread p owns chunks {p, p+16}, so a wave's 16
// lanes read 256 contiguous bytes of a row (coalesced global, 2-way-free
// LDS banking with broadcast across the 4 row-groups in the wave).
__global__ __launch_bounds__(THREADS, 4) void hs_kernel(
    const float* __restrict__ xw,      // (B, D)
    const float* __restrict__ W,       // (N, D)
    const float* __restrict__ h_code,  // (L,)
    const int*   __restrict__ h_path,  // (L,)
    float* __restrict__ out)           // (B, 1)
{
    __shared__ float4 Ws[LL * CHUNKS];   // 20 rows x 32 float4 = 10 KB
    __shared__ float  codes[LL];

    const int tid = threadIdx.x;
    const int p   = tid & (TPR - 1);     // which 16th of D
    const int r   = tid >> 4;            // row within block
    const int row = blockIdx.x * RPB + r;
    const float4* x4 = (const float4*)xw + (size_t)row * CHUNKS;

    // Prefetch this thread's xw chunks BEFORE staging W: the x HBM latency
    // hides under the gather chain + barrier instead of being exposed after.
    const float4 x0 = x4[p];
    const float4 x1 = x4[p + TPR];

    // Stage gathered W rows into LDS (640 float4 over 256 threads)
    for (int i = tid; i < LL * CHUNKS; i += THREADS) {
        const int l = i >> 5;            // path index
        const int c = i & (CHUNKS - 1);  // float4 chunk within row
        Ws[i] = ((const float4*)W)[(long long)h_path[l] * CHUNKS + c];
    }
    if (tid < LL) codes[tid] = h_code[tid];
    __syncthreads();

    // Partial dot products: 2 chunks x 20 path rows, 40 ds_read_b128/thread
    float z[LL];
#pragma unroll
    for (int l = 0; l < LL; ++l) {
        const float4 w0 = Ws[l * CHUNKS + p];
        const float4 w1 = Ws[l * CHUNKS + p + TPR];
        z[l] = x0.x * w0.x + x0.y * w0.y + x0.z * w0.z + x0.w * w0.w
             + x1.x * w1.x + x1.y * w1.y + x1.z * w1.z + x1.w * w1.w;
    }

    // 16-lane butterfly per row group (xor masks < 16 stay within group)
#pragma unroll
    for (int l = 0; l < LL; ++l) {
        z[l] += __shfl_xor(z[l], 1);
        z[l] += __shfl_xor(z[l], 2);
        z[l] += __shfl_xor(z[l], 4);
        z[l] += __shfl_xor(z[l], 8);
    }

    if (p == 0) {
        // p_l = code*log_sigmoid(z) + (1-code)*log_sigmoid(-z)
        //     = -softplus(-z) - (1-code)*z   (exact identity)
        // Compile-time indices only: z[runtime] would spill the whole
        // array to scratch. The 20 chains are independent -> ILP covers
        // the transcendental latency; only 4/64 lanes run this tail.
        float s = 0.0f;
#pragma unroll
        for (int l = 0; l < LL; ++l) {
            const float zl = z[l];
            const float t  = -zl;
            const float sp = fmaxf(t, 0.0f) + log1pf(expf(-fabsf(t)));
            s -= sp + (1.0f - codes[l]) * zl;
        }
        out[row] = s;   // lanes 0,16,32,48 -> 4 consecutive rows, coalesced
    }
}

extern "C" void kernel_launch(void* const* d_in, const int* in_sizes, int n_in,
                              void* d_out, int out_size, void* d_ws, size_t ws_size,
                              hipStream_t stream) {
    const float* xw     = (const float*)d_in[0];
    const float* W      = (const float*)d_in[1];
    const float* h_code = (const float*)d_in[2];
    const int*   h_path = (const int*)d_in[3];
    float* out = (float*)d_out;

    hs_kernel<<<BB / RPB, THREADS, 0, stream>>>(xw, W, h_code, h_path, out);
}